// Round 2
// baseline (35676.996 us; speedup 1.0000x reference)
//
#include <hip/hip_runtime.h>
#include <float.h>
#include <math.h>
#include <stdint.h>

#define M_ROWS 32768
#define K_CODES 8192
#define DDIM 256
#define BM 128
#define BN 64
#define NTILES (K_CODES / BN)   // 128
#define CAP 24
#define DELTA 0.009f

typedef __attribute__((ext_vector_type(8))) short short8;
typedef __attribute__((ext_vector_type(4))) float f32x4;

__device__ inline unsigned short f2bf(float f) {
    unsigned u = __float_as_uint(f);
    return (unsigned short)((u + 0x7fffu + ((u >> 16) & 1u)) >> 16);
}

#define GLOAD16(gsrc, ldst)                                                     \
    __builtin_amdgcn_global_load_lds(                                           \
        (const __attribute__((address_space(1))) void*)(gsrc),                  \
        (__attribute__((address_space(3))) void*)(ldst), 16, 0, 0)

// ---------------- kernel 1: normalize E -> En (fp32) + En_b (bf16) ----------------
__global__ __launch_bounds__(256) void k_norm_E(const float* __restrict__ E,
                                                float* __restrict__ En,
                                                unsigned short* __restrict__ En_b) {
    int wid  = threadIdx.x >> 6;
    int lane = threadIdx.x & 63;
    int row  = blockIdx.x * 4 + wid;
    const float* e = E + (size_t)row * DDIM;
    float v[4];
    float ssq = 0.f;
#pragma unroll
    for (int p = 0; p < 4; ++p) { v[p] = e[lane + 64 * p]; ssq += v[p] * v[p]; }
#pragma unroll
    for (int off = 32; off >= 1; off >>= 1) ssq += __shfl_xor(ssq, off);
    float inv = 1.f / fmaxf(sqrtf(ssq), 1e-8f);
    float* o = En + (size_t)row * DDIM;
    unsigned short* ob = En_b + (size_t)row * DDIM;
#pragma unroll
    for (int p = 0; p < 4; ++p) {
        float nv = v[p] * inv;
        o[lane + 64 * p]  = nv;
        ob[lane + 64 * p] = f2bf(nv);
    }
}

// ---------------- kernel 1b: normalize z -> z_nb (bf16) ----------------
__global__ __launch_bounds__(256) void k_norm_z(const float* __restrict__ z,
                                                unsigned short* __restrict__ z_nb) {
    int wid  = threadIdx.x >> 6;
    int lane = threadIdx.x & 63;
    int row  = blockIdx.x * 4 + wid;
    const float* zr = z + (size_t)row * DDIM;
    float v[4];
    float ssq = 0.f;
#pragma unroll
    for (int p = 0; p < 4; ++p) { v[p] = zr[lane + 64 * p]; ssq += v[p] * v[p]; }
#pragma unroll
    for (int off = 32; off >= 1; off >>= 1) ssq += __shfl_xor(ssq, off);
    float inv = 1.f / fmaxf(sqrtf(ssq), 1e-8f);
    unsigned short* o = z_nb + (size_t)row * DDIM;
#pragma unroll
    for (int p = 0; p < 4; ++p) o[lane + 64 * p] = f2bf(v[p] * inv);
}

// ---------------- kernel 2: MFMA filter + exact fp32 rescore ----------------
// Block: 256 thr = 4 waves (wr = wave>>1 row-half, wc = wave&1 col-half).
// BM=128 z-rows resident (A-frags in registers), loop 128 tiles of BN=64 E-rows.
// LDS XOR-swizzle: 16B granule g' = g ^ (row&7); staged linearly with
// pre-swizzled global source (global_load_lds writes linear), read with swizzle.
__global__ __launch_bounds__(256, 1) void k_cand(
    const unsigned short* __restrict__ z_nb,
    const unsigned short* __restrict__ En_b,
    const float* __restrict__ z,
    const float* __restrict__ En,
    int* __restrict__ bestIdx) {

    __shared__ unsigned short As[BM * DDIM];       // 64 KB
    __shared__ unsigned short Bs[2][BN * DDIM];    // 2 x 32 KB
    __shared__ int cnt[BM];
    __shared__ int list[BM][CAP];                  // 12 KB

    const int tid  = threadIdx.x;
    const int lane = tid & 63;
    const int wid  = tid >> 6;
    const int wr   = wid >> 1;
    const int wc   = wid & 1;
    const int lo   = lane & 15;
    const int hi   = lane >> 4;
    const int m0   = blockIdx.x * BM;

    if (tid < BM) cnt[tid] = 0;

    const char* zb = (const char*)z_nb;
    const char* eb = (const char*)En_b;

    // ---- prologue staging: A (64 KB) + B tile 0 (32 KB) ----
#pragma unroll
    for (int i = 0; i < 16; ++i) {
        int chunk = i * 4 + wid;            // 0..63
        int G   = chunk * 64 + lane;        // 16B granule id
        int row = G >> 5;
        int g   = (G & 31) ^ (row & 7);
        GLOAD16(zb + (size_t)(m0 + row) * 512 + g * 16, (char*)As + chunk * 1024);
    }
#pragma unroll
    for (int i = 0; i < 8; ++i) {
        int chunk = i * 4 + wid;            // 0..31
        int G   = chunk * 64 + lane;
        int row = G >> 5;
        int g   = (G & 31) ^ (row & 7);
        GLOAD16(eb + (size_t)row * 512 + g * 16, (char*)&Bs[0][0] + chunk * 1024);
    }
    asm volatile("s_waitcnt vmcnt(0)");
    __syncthreads();

    // ---- load A fragments into registers: af[mi][ks], row = wr*64+mi*16+lo ----
    short8 af[4][8];
#pragma unroll
    for (int mi = 0; mi < 4; ++mi) {
        int row = wr * 64 + mi * 16 + lo;
        int sw  = row & 7;
#pragma unroll
        for (int ks = 0; ks < 8; ++ks) {
            int g = (ks * 4 + hi) ^ sw;
            af[mi][ks] = *(const short8*)&As[row * 256 + g * 8];
        }
    }

    float thr[16];
#pragma unroll
    for (int i = 0; i < 16; ++i) thr[i] = -FLT_MAX;

    int cur = 0;
    for (int t = 0; t < NTILES; ++t) {
        // stage next B tile into buf cur^1 (overlaps compute below)
        if (t + 1 < NTILES) {
            int kt1 = (t + 1) * BN;
#pragma unroll
            for (int i = 0; i < 8; ++i) {
                int chunk = i * 4 + wid;
                int G   = chunk * 64 + lane;
                int row = G >> 5;
                int g   = (G & 31) ^ (row & 7);
                GLOAD16(eb + (size_t)(kt1 + row) * 512 + g * 16,
                        (char*)&Bs[cur ^ 1][0] + chunk * 1024);
            }
        }

        f32x4 acc[4][2];
#pragma unroll
        for (int mi = 0; mi < 4; ++mi)
#pragma unroll
            for (int nj = 0; nj < 2; ++nj) acc[mi][nj] = (f32x4){0.f, 0.f, 0.f, 0.f};

        const unsigned short* Bc = &Bs[cur][0];
#pragma unroll
        for (int ks = 0; ks < 8; ++ks) {
            short8 bf0, bf1;
            {
                int row = wc * 32 + lo;                 // nj=0
                int g   = (ks * 4 + hi) ^ (row & 7);
                bf0 = *(const short8*)&Bc[row * 256 + g * 8];
            }
            {
                int row = wc * 32 + 16 + lo;            // nj=1
                int g   = (ks * 4 + hi) ^ (row & 7);
                bf1 = *(const short8*)&Bc[row * 256 + g * 8];
            }
#pragma unroll
            for (int mi = 0; mi < 4; ++mi) {
                acc[mi][0] = __builtin_amdgcn_mfma_f32_16x16x32_bf16(af[mi][ks], bf0, acc[mi][0], 0, 0, 0);
                acc[mi][1] = __builtin_amdgcn_mfma_f32_16x16x32_bf16(af[mi][ks], bf1, acc[mi][1], 0, 0, 0);
            }
        }

        const int kt = t * BN;
        if (t == 0) {
            // seed thr with cross-lane row max of tile 0 (this wave's 32 cols)
#pragma unroll
            for (int mi = 0; mi < 4; ++mi)
#pragma unroll
                for (int r = 0; r < 4; ++r) {
                    float mv = fmaxf(acc[mi][0][r], acc[mi][1][r]);
                    mv = fmaxf(mv, __shfl_xor(mv, 1));
                    mv = fmaxf(mv, __shfl_xor(mv, 2));
                    mv = fmaxf(mv, __shfl_xor(mv, 4));
                    mv = fmaxf(mv, __shfl_xor(mv, 8));
                    thr[mi * 4 + r] = mv - DELTA;
                }
        }

        // fold: record candidates within DELTA of (lane-local lower bound of) row max
#pragma unroll
        for (int mi = 0; mi < 4; ++mi)
#pragma unroll
            for (int nj = 0; nj < 2; ++nj)
#pragma unroll
                for (int r = 0; r < 4; ++r) {
                    float v = acc[mi][nj][r];
                    int i = mi * 4 + r;
                    if (v >= thr[i]) {
                        int rloc = wr * 64 + mi * 16 + hi * 4 + r;
                        int kg   = kt + wc * 32 + nj * 16 + lo;
                        int pos  = atomicAdd(&cnt[rloc], 1);
                        if (pos < CAP) list[rloc][pos] = kg;
                        thr[i] = fmaxf(thr[i], v - DELTA);
                    }
                }

        __syncthreads();
        cur ^= 1;
    }

    // ---- exact fp32 rescore of candidates (order-independent, deterministic) ----
    for (int rr = 0; rr < 32; ++rr) {
        int rloc = wid * 32 + rr;
        int m = m0 + rloc;
        int n = cnt[rloc];
        float bv = -FLT_MAX;
        int   bk = 0x7fffffff;
        if (n <= CAP) {
            const float4 zz = *(const float4*)&z[(size_t)m * DDIM + lane * 4];
            for (int c = 0; c < n; ++c) {
                int k = list[rloc][c];
                const float4 ee = *(const float4*)&En[(size_t)k * DDIM + lane * 4];
                float s = zz.x * ee.x + zz.y * ee.y + zz.z * ee.z + zz.w * ee.w;
#pragma unroll
                for (int off = 1; off < 64; off <<= 1) s += __shfl_xor(s, off);
                if (s > bv || (s == bv && k < bk)) { bv = s; bk = k; }
            }
        } else {
            // overflow fallback: deterministic full fp32 row scan (expected never)
            for (int k = lane; k < K_CODES; k += 64) {
                float s = 0.f;
                for (int d4 = 0; d4 < 64; ++d4) {
                    const float4 zz = *(const float4*)&z[(size_t)m * DDIM + d4 * 4];
                    const float4 ee = *(const float4*)&En[(size_t)k * DDIM + d4 * 4];
                    s += zz.x * ee.x; s += zz.y * ee.y; s += zz.z * ee.z; s += zz.w * ee.w;
                }
                if (s > bv || (s == bv && k < bk)) { bv = s; bk = k; }
            }
#pragma unroll
            for (int off = 1; off < 64; off <<= 1) {
                float ov = __shfl_xor(bv, off);
                int   ok = __shfl_xor(bk, off);
                if (ov > bv || (ov == bv && ok < bk)) { bv = ov; bk = ok; }
            }
        }
        if (lane == 0) bestIdx[m] = bk;
    }
}

// ---------------- kernel 3: gather / zq_st / per-row loss / idx ----------------
__global__ __launch_bounds__(256) void k_final(const float* __restrict__ z,
                                               const float* __restrict__ E,
                                               const int* __restrict__ bestIdx,
                                               float* __restrict__ out,
                                               float* __restrict__ rowloss) {
    int wid  = threadIdx.x >> 6;
    int lane = threadIdx.x & 63;
    int m    = blockIdx.x * 4 + wid;
    int idx  = bestIdx[m];

    const float* zr = z + (size_t)m * DDIM;
    const float* er = E + (size_t)idx * DDIM;

    float zv[4], ev[4];
    float sz = 0.f, se = 0.f;
#pragma unroll
    for (int p = 0; p < 4; ++p) {
        zv[p] = zr[lane + 64 * p]; sz += zv[p] * zv[p];
        ev[p] = er[lane + 64 * p]; se += ev[p] * ev[p];
    }
#pragma unroll
    for (int off = 32; off >= 1; off >>= 1) {
        sz += __shfl_xor(sz, off);
        se += __shfl_xor(se, off);
    }
    float nz = fmaxf(sqrtf(sz), 1e-8f);
    float ne = fmaxf(sqrtf(se), 1e-8f);

    float rs = 0.f;
    float* zq = out + 1 + (size_t)m * DDIM;
#pragma unroll
    for (int p = 0; p < 4; ++p) {
        float zn = zv[p] / nz;
        float en = ev[p] / ne;
        float d  = en - zn;
        rs += d * d;
        zq[lane + 64 * p] = zv[p] + (ev[p] - zv[p]);
    }
#pragma unroll
    for (int off = 32; off >= 1; off >>= 1) rs += __shfl_xor(rs, off);

    if (lane == 0) {
        rowloss[m] = rs;
        out[1 + (size_t)M_ROWS * DDIM + m] = (float)idx;
    }
}

// ---------------- kernel 4: deterministic loss reduction ----------------
__global__ __launch_bounds__(256) void k_loss(const float* __restrict__ rowloss,
                                              float* __restrict__ out) {
    __shared__ double sm[256];
    double s = 0.0;
    for (int i = threadIdx.x; i < M_ROWS; i += 256) s += (double)rowloss[i];
    sm[threadIdx.x] = s;
    __syncthreads();
    for (int st = 128; st > 0; st >>= 1) {
        if (threadIdx.x < st) sm[threadIdx.x] += sm[threadIdx.x + st];
        __syncthreads();
    }
    if (threadIdx.x == 0) {
        float c = (float)(sm[0] / (double)((size_t)M_ROWS * DDIM));
        out[0] = c + 0.05f * c;
    }
}

extern "C" void kernel_launch(void* const* d_in, const int* in_sizes, int n_in,
                              void* d_out, int out_size, void* d_ws, size_t ws_size,
                              hipStream_t stream) {
    const float* z = (const float*)d_in[0];
    const float* E = (const float*)d_in[1];
    float* out = (float*)d_out;

    char* ws = (char*)d_ws;
    size_t off = 0;
    float*          En      = (float*)(ws + off);          off += (size_t)K_CODES * DDIM * 4;  // 8 MB
    unsigned short* En_b    = (unsigned short*)(ws + off); off += (size_t)K_CODES * DDIM * 2;  // 4 MB
    unsigned short* z_nb    = (unsigned short*)(ws + off); off += (size_t)M_ROWS * DDIM * 2;   // 16 MB
    int*            bestIdx = (int*)(ws + off);            off += (size_t)M_ROWS * 4;          // 128 KB
    float*          rowloss = (float*)(ws + off);

    k_norm_E<<<K_CODES / 4, 256, 0, stream>>>(E, En, En_b);
    k_norm_z<<<M_ROWS / 4, 256, 0, stream>>>(z, z_nb);
    k_cand<<<M_ROWS / BM, 256, 0, stream>>>(z_nb, En_b, z, En, bestIdx);
    k_final<<<M_ROWS / 4, 256, 0, stream>>>(z, E, bestIdx, out, rowloss);
    k_loss<<<1, 256, 0, stream>>>(rowloss, out);
}

// Round 3
// 2019.416 us; speedup vs baseline: 17.6670x; 17.6670x over previous
//
#include <hip/hip_runtime.h>
#include <float.h>
#include <math.h>
#include <stdint.h>

#define M_ROWS 32768
#define K_CODES 8192
#define DDIM 256
#define BM 128
#define BN 64
#define NTILES (K_CODES / BN)   // 128
#define CAP 20
#define DELTA 0.009f

typedef __attribute__((ext_vector_type(8))) short short8;
typedef __attribute__((ext_vector_type(4))) float f32x4;

__device__ inline unsigned short f2bf(float f) {
    unsigned u = __float_as_uint(f);
    return (unsigned short)((u + 0x7fffu + ((u >> 16) & 1u)) >> 16);
}

// monotone int key for float atomicMax (works for negatives)
__device__ inline unsigned fkey(float f) {
    unsigned u = __float_as_uint(f);
    return u ^ ((unsigned)((int)u >> 31) | 0x80000000u);
}
__device__ inline float fkey_inv(unsigned k) {
    unsigned u = (k & 0x80000000u) ? (k ^ 0x80000000u) : ~k;
    return __uint_as_float(u);
}

#define GLOAD16(gsrc, ldst)                                                     \
    __builtin_amdgcn_global_load_lds(                                           \
        (const __attribute__((address_space(1))) void*)(gsrc),                  \
        (__attribute__((address_space(3))) void*)(ldst), 16, 0, 0)

// ---------------- kernel 1: normalize E -> En (fp32) + En_b (bf16) ----------------
__global__ __launch_bounds__(256) void k_norm_E(const float* __restrict__ E,
                                                float* __restrict__ En,
                                                unsigned short* __restrict__ En_b) {
    int wid  = threadIdx.x >> 6;
    int lane = threadIdx.x & 63;
    int row  = blockIdx.x * 4 + wid;
    const float* e = E + (size_t)row * DDIM;
    float v[4];
    float ssq = 0.f;
#pragma unroll
    for (int p = 0; p < 4; ++p) { v[p] = e[lane + 64 * p]; ssq += v[p] * v[p]; }
#pragma unroll
    for (int off = 32; off >= 1; off >>= 1) ssq += __shfl_xor(ssq, off);
    float inv = 1.f / fmaxf(sqrtf(ssq), 1e-8f);
    float* o = En + (size_t)row * DDIM;
    unsigned short* ob = En_b + (size_t)row * DDIM;
#pragma unroll
    for (int p = 0; p < 4; ++p) {
        float nv = v[p] * inv;
        o[lane + 64 * p]  = nv;
        ob[lane + 64 * p] = f2bf(nv);
    }
}

// ---------------- kernel 1b: normalize z -> z_nb (bf16) ----------------
__global__ __launch_bounds__(256) void k_norm_z(const float* __restrict__ z,
                                                unsigned short* __restrict__ z_nb) {
    int wid  = threadIdx.x >> 6;
    int lane = threadIdx.x & 63;
    int row  = blockIdx.x * 4 + wid;
    const float* zr = z + (size_t)row * DDIM;
    float v[4];
    float ssq = 0.f;
#pragma unroll
    for (int p = 0; p < 4; ++p) { v[p] = zr[lane + 64 * p]; ssq += v[p] * v[p]; }
#pragma unroll
    for (int off = 32; off >= 1; off >>= 1) ssq += __shfl_xor(ssq, off);
    float inv = 1.f / fmaxf(sqrtf(ssq), 1e-8f);
    unsigned short* o = z_nb + (size_t)row * DDIM;
#pragma unroll
    for (int p = 0; p < 4; ++p) o[lane + 64 * p] = f2bf(v[p] * inv);
}

// ---------------- kernel 2: MFMA filter + exact fp32 rescore ----------------
// 4 waves: wr=wid>>1 (row half of BM=128), wc=wid&1 (col half of BN=64).
// A-fragments in registers; B double-buffered in LDS (XOR-swizzled granules,
// staged linearly with pre-swizzled global source). Shared per-row prefix max
// via LDS atomicMax(int-key) -> tight candidate threshold.
__global__ __launch_bounds__(256, 2) void k_cand(
    const unsigned short* __restrict__ z_nb,
    const unsigned short* __restrict__ En_b,
    const float* __restrict__ z,
    const float* __restrict__ En,
    int* __restrict__ bestIdx) {

    // LDS union: A staging (64KB, prologue only) overlaps B double buffer (2x32KB)
    __shared__ __attribute__((aligned(16))) char smem[65536 + BM * CAP * 4 + 512 + 512];
    unsigned short* As  = (unsigned short*)smem;
    char*           Bs0 = smem;
    char*           Bs1 = smem + 32768;
    int*      list      = (int*)(smem + 65536);
    int*      cnt       = (int*)(smem + 65536 + BM * CAP * 4);
    unsigned* rowmaxKey = (unsigned*)(smem + 65536 + BM * CAP * 4 + 512);

    const int tid  = threadIdx.x;
    const int lane = tid & 63;
    const int wid  = tid >> 6;
    const int wr   = wid >> 1;
    const int wc   = wid & 1;
    const int lo   = lane & 15;
    const int hi   = lane >> 4;
    const int m0   = blockIdx.x * BM;

    if (tid < BM) { cnt[tid] = 0; rowmaxKey[tid] = 0u; }

    const char* zb = (const char*)z_nb;
    const char* eb = (const char*)En_b;

    // ---- prologue: stage A (64 KB) ----
#pragma unroll
    for (int i = 0; i < 16; ++i) {
        int chunk = i * 4 + wid;            // 0..63 (1KB chunks)
        int G   = chunk * 64 + lane;        // granule 0..4095
        int row = G >> 5;
        int g   = (G & 31) ^ (row & 7);
        GLOAD16(zb + (size_t)(m0 + row) * 512 + g * 16, (char*)As + chunk * 1024);
    }
    asm volatile("s_waitcnt vmcnt(0)");
    __syncthreads();

    // ---- A fragments -> registers ----
    short8 af[4][8];
#pragma unroll
    for (int mi = 0; mi < 4; ++mi) {
        int row = wr * 64 + mi * 16 + lo;
        int sw  = row & 7;
#pragma unroll
        for (int ks = 0; ks < 8; ++ks) {
            int g = (ks * 4 + hi) ^ sw;
            af[mi][ks] = *(const short8*)&As[row * 256 + g * 8];
        }
    }
    __syncthreads();   // A region dead; safe to overwrite with B tiles

    // ---- stage B tile 0 ----
#pragma unroll
    for (int i = 0; i < 8; ++i) {
        int chunk = i * 4 + wid;            // 0..31
        int G   = chunk * 64 + lane;        // granule 0..2047
        int row = G >> 5;
        int g   = (G & 31) ^ (row & 7);
        GLOAD16(eb + (size_t)row * 512 + g * 16, Bs0 + chunk * 1024);
    }
    asm volatile("s_waitcnt vmcnt(0)");
    __syncthreads();

    int cur = 0;
    for (int t = 0; t < NTILES; ++t) {
        // prefetch next B tile into the other buffer (drained at this tile's barrier)
        if (t + 1 < NTILES) {
            int kt1 = (t + 1) * BN;
            char* dst = cur ? Bs0 : Bs1;
#pragma unroll
            for (int i = 0; i < 8; ++i) {
                int chunk = i * 4 + wid;
                int G   = chunk * 64 + lane;
                int row = G >> 5;
                int g   = (G & 31) ^ (row & 7);
                GLOAD16(eb + (size_t)(kt1 + row) * 512 + g * 16, dst + chunk * 1024);
            }
        }

        f32x4 acc[4][2];
#pragma unroll
        for (int mi = 0; mi < 4; ++mi)
#pragma unroll
            for (int nj = 0; nj < 2; ++nj) acc[mi][nj] = (f32x4){0.f, 0.f, 0.f, 0.f};

        const unsigned short* Bc = (const unsigned short*)(cur ? Bs1 : Bs0);
#pragma unroll
        for (int ks = 0; ks < 8; ++ks) {
            short8 bf0, bf1;
            {
                int row = wc * 32 + lo;
                int g   = (ks * 4 + hi) ^ (row & 7);
                bf0 = *(const short8*)&Bc[row * 256 + g * 8];
            }
            {
                int row = wc * 32 + 16 + lo;
                int g   = (ks * 4 + hi) ^ (row & 7);
                bf1 = *(const short8*)&Bc[row * 256 + g * 8];
            }
#pragma unroll
            for (int mi = 0; mi < 4; ++mi) {
                acc[mi][0] = __builtin_amdgcn_mfma_f32_16x16x32_bf16(af[mi][ks], bf0, acc[mi][0], 0, 0, 0);
                acc[mi][1] = __builtin_amdgcn_mfma_f32_16x16x32_bf16(af[mi][ks], bf1, acc[mi][1], 0, 0, 0);
            }
        }

        // ---- fold: update shared per-row prefix max (this wave's 32 cols) ----
#pragma unroll
        for (int mi = 0; mi < 4; ++mi)
#pragma unroll
            for (int r = 0; r < 4; ++r) {
                float v2 = fmaxf(acc[mi][0][r], acc[mi][1][r]);
                v2 = fmaxf(v2, __shfl_xor(v2, 1));
                v2 = fmaxf(v2, __shfl_xor(v2, 2));
                v2 = fmaxf(v2, __shfl_xor(v2, 4));
                v2 = fmaxf(v2, __shfl_xor(v2, 8));
                if (lo == 0) {
                    int rloc = wr * 64 + mi * 16 + hi * 4 + r;
                    atomicMax(&rowmaxKey[rloc], fkey(v2));
                }
            }

        __syncthreads();   // rowmax fresh + prefetch drained + dbuf safe

        // ---- candidate check vs global prefix max (incl. this tile) ----
        const int kt = t * BN;
#pragma unroll
        for (int mi = 0; mi < 4; ++mi)
#pragma unroll
            for (int r = 0; r < 4; ++r) {
                int rloc = wr * 64 + mi * 16 + hi * 4 + r;
                float thr = fkey_inv(rowmaxKey[rloc]) - DELTA;
#pragma unroll
                for (int nj = 0; nj < 2; ++nj) {
                    float v = acc[mi][nj][r];
                    if (v >= thr) {
                        int pos = atomicAdd(&cnt[rloc], 1);
                        if (pos < CAP) list[rloc * CAP + pos] = kt + wc * 32 + nj * 16 + lo;
                    }
                }
            }

        cur ^= 1;
    }
    __syncthreads();   // lists complete before rescore

    // ---- exact fp32 rescore (order-independent, deterministic) ----
    for (int rr = 0; rr < 32; ++rr) {
        int rloc = wid * 32 + rr;
        int m = m0 + rloc;
        int n = cnt[rloc];
        float bv = -FLT_MAX;
        int   bk = 0x7fffffff;
        if (n <= CAP) {
            const float4 zz = *(const float4*)&z[(size_t)m * DDIM + lane * 4];
            for (int c = 0; c < n; ++c) {
                int k = list[rloc * CAP + c];
                const float4 ee = *(const float4*)&En[(size_t)k * DDIM + lane * 4];
                float s = zz.x * ee.x + zz.y * ee.y + zz.z * ee.z + zz.w * ee.w;
#pragma unroll
                for (int off = 1; off < 64; off <<= 1) s += __shfl_xor(s, off);
                if (s > bv || (s == bv && k < bk)) { bv = s; bk = k; }
            }
        } else {
            // overflow fallback: deterministic full fp32 row scan (expected never)
            for (int k = lane; k < K_CODES; k += 64) {
                float s = 0.f;
                for (int d4 = 0; d4 < 64; ++d4) {
                    const float4 zz = *(const float4*)&z[(size_t)m * DDIM + d4 * 4];
                    const float4 ee = *(const float4*)&En[(size_t)k * DDIM + d4 * 4];
                    s += zz.x * ee.x; s += zz.y * ee.y; s += zz.z * ee.z; s += zz.w * ee.w;
                }
                if (s > bv || (s == bv && k < bk)) { bv = s; bk = k; }
            }
#pragma unroll
            for (int off = 1; off < 64; off <<= 1) {
                float ov = __shfl_xor(bv, off);
                int   ok = __shfl_xor(bk, off);
                if (ov > bv || (ov == bv && ok < bk)) { bv = ov; bk = ok; }
            }
        }
        if (lane == 0) bestIdx[m] = bk;
    }
}

// ---------------- kernel 3: gather / zq_st / per-row loss / idx ----------------
__global__ __launch_bounds__(256) void k_final(const float* __restrict__ z,
                                               const float* __restrict__ E,
                                               const int* __restrict__ bestIdx,
                                               float* __restrict__ out,
                                               float* __restrict__ rowloss) {
    int wid  = threadIdx.x >> 6;
    int lane = threadIdx.x & 63;
    int m    = blockIdx.x * 4 + wid;
    int idx  = bestIdx[m];

    const float* zr = z + (size_t)m * DDIM;
    const float* er = E + (size_t)idx * DDIM;

    float zv[4], ev[4];
    float sz = 0.f, se = 0.f;
#pragma unroll
    for (int p = 0; p < 4; ++p) {
        zv[p] = zr[lane + 64 * p]; sz += zv[p] * zv[p];
        ev[p] = er[lane + 64 * p]; se += ev[p] * ev[p];
    }
#pragma unroll
    for (int off = 32; off >= 1; off >>= 1) {
        sz += __shfl_xor(sz, off);
        se += __shfl_xor(se, off);
    }
    float nz = fmaxf(sqrtf(sz), 1e-8f);
    float ne = fmaxf(sqrtf(se), 1e-8f);

    float rs = 0.f;
    float* zq = out + 1 + (size_t)m * DDIM;
#pragma unroll
    for (int p = 0; p < 4; ++p) {
        float zn = zv[p] / nz;
        float en = ev[p] / ne;
        float d  = en - zn;
        rs += d * d;
        zq[lane + 64 * p] = zv[p] + (ev[p] - zv[p]);
    }
#pragma unroll
    for (int off = 32; off >= 1; off >>= 1) rs += __shfl_xor(rs, off);

    if (lane == 0) {
        rowloss[m] = rs;
        out[1 + (size_t)M_ROWS * DDIM + m] = (float)idx;
    }
}

// ---------------- kernel 4: deterministic loss reduction ----------------
__global__ __launch_bounds__(256) void k_loss(const float* __restrict__ rowloss,
                                              float* __restrict__ out) {
    __shared__ double sm[256];
    double s = 0.0;
    for (int i = threadIdx.x; i < M_ROWS; i += 256) s += (double)rowloss[i];
    sm[threadIdx.x] = s;
    __syncthreads();
    for (int st = 128; st > 0; st >>= 1) {
        if (threadIdx.x < st) sm[threadIdx.x] += sm[threadIdx.x + st];
        __syncthreads();
    }
    if (threadIdx.x == 0) {
        float c = (float)(sm[0] / (double)((size_t)M_ROWS * DDIM));
        out[0] = c + 0.05f * c;
    }
}

extern "C" void kernel_launch(void* const* d_in, const int* in_sizes, int n_in,
                              void* d_out, int out_size, void* d_ws, size_t ws_size,
                              hipStream_t stream) {
    const float* z = (const float*)d_in[0];
    const float* E = (const float*)d_in[1];
    float* out = (float*)d_out;

    char* ws = (char*)d_ws;
    size_t off = 0;
    float*          En      = (float*)(ws + off);          off += (size_t)K_CODES * DDIM * 4;  // 8 MB
    unsigned short* En_b    = (unsigned short*)(ws + off); off += (size_t)K_CODES * DDIM * 2;  // 4 MB
    unsigned short* z_nb    = (unsigned short*)(ws + off); off += (size_t)M_ROWS * DDIM * 2;   // 16 MB
    int*            bestIdx = (int*)(ws + off);            off += (size_t)M_ROWS * 4;          // 128 KB
    float*          rowloss = (float*)(ws + off);

    k_norm_E<<<K_CODES / 4, 256, 0, stream>>>(E, En, En_b);
    k_norm_z<<<M_ROWS / 4, 256, 0, stream>>>(z, z_nb);
    k_cand<<<M_ROWS / BM, 256, 0, stream>>>(z_nb, En_b, z, En, bestIdx);
    k_final<<<M_ROWS / 4, 256, 0, stream>>>(z, E, bestIdx, out, rowloss);
    k_loss<<<1, 256, 0, stream>>>(rowloss, out);
}

// Round 4
// 1913.918 us; speedup vs baseline: 18.6408x; 1.0551x over previous
//
#include <hip/hip_runtime.h>
#include <float.h>
#include <math.h>
#include <stdint.h>

#define M_ROWS 32768
#define K_CODES 8192
#define DDIM 256
#define BM 128
#define BN 64
#define NTILES (K_CODES / BN)   // 128
#define CAP 48
#define DELTA 0.009f

typedef __attribute__((ext_vector_type(8))) short short8;
typedef __attribute__((ext_vector_type(4))) float f32x4;

__device__ inline unsigned short f2bf(float f) {
    unsigned u = __float_as_uint(f);
    return (unsigned short)((u + 0x7fffu + ((u >> 16) & 1u)) >> 16);
}

// monotone unsigned key for float atomicMax (handles negatives)
__device__ inline unsigned fkey(float f) {
    unsigned u = __float_as_uint(f);
    return u ^ ((unsigned)((int)u >> 31) | 0x80000000u);
}
__device__ inline float fkey_inv(unsigned k) {
    unsigned u = (k & 0x80000000u) ? (k ^ 0x80000000u) : ~k;
    return __uint_as_float(u);
}

#define GLOAD16(gsrc, ldst)                                                     \
    __builtin_amdgcn_global_load_lds(                                           \
        (const __attribute__((address_space(1))) void*)(gsrc),                  \
        (__attribute__((address_space(3))) void*)(ldst), 16, 0, 0)

// ---------------- kernel 1: normalize E -> En (fp32) + En_b (bf16) ----------------
__global__ __launch_bounds__(256) void k_norm_E(const float* __restrict__ E,
                                                float* __restrict__ En,
                                                unsigned short* __restrict__ En_b) {
    int wid  = threadIdx.x >> 6;
    int lane = threadIdx.x & 63;
    int row  = blockIdx.x * 4 + wid;
    const float* e = E + (size_t)row * DDIM;
    float v[4];
    float ssq = 0.f;
#pragma unroll
    for (int p = 0; p < 4; ++p) { v[p] = e[lane + 64 * p]; ssq += v[p] * v[p]; }
#pragma unroll
    for (int off = 32; off >= 1; off >>= 1) ssq += __shfl_xor(ssq, off);
    float inv = 1.f / fmaxf(sqrtf(ssq), 1e-8f);
    float* o = En + (size_t)row * DDIM;
    unsigned short* ob = En_b + (size_t)row * DDIM;
#pragma unroll
    for (int p = 0; p < 4; ++p) {
        float nv = v[p] * inv;
        o[lane + 64 * p]  = nv;
        ob[lane + 64 * p] = f2bf(nv);
    }
}

// ---------------- kernel 2: fused z-norm + MFMA filter + exact fp32 rescore ----------------
// 512 threads = 8 waves: wr=wid>>1 (0..3) owns 32 rows, wc=wid&1 owns 32 cols.
// A (z_n bf16) normalized in-kernel into swizzled LDS, then register fragments.
// B double-buffered via global_load_lds with pre-swizzled source.
// Per-lane register prefix max; shared rowmax refreshed every 8 tiles (conservative).
__global__ __launch_bounds__(512, 1) void k_cand(
    const unsigned short* __restrict__ En_b,
    const float* __restrict__ z,
    const float* __restrict__ En,
    int* __restrict__ bestIdx) {

    __shared__ __attribute__((aligned(16)))
    char smem[65536 + 32768 + 32768 + BM * CAP * 4 + 512 + 512];
    unsigned short* As  = (unsigned short*)smem;            // 64 KB (z_n bf16)
    char*           Bs0 = smem + 65536;                     // 32 KB
    char*           Bs1 = smem + 65536 + 32768;             // 32 KB
    int*      list      = (int*)(smem + 131072);            // 24 KB
    int*      cnt       = (int*)(smem + 131072 + BM * CAP * 4);
    unsigned* rowmaxKey = (unsigned*)(smem + 131072 + BM * CAP * 4 + 512);

    const int tid  = threadIdx.x;
    const int lane = tid & 63;
    const int wid  = tid >> 6;
    const int wr   = wid >> 1;
    const int wc   = wid & 1;
    const int lo   = lane & 15;
    const int hi   = lane >> 4;
    const int m0   = blockIdx.x * BM;

    if (tid < BM) { cnt[tid] = 0; rowmaxKey[tid] = 0u; }

    const char* eb = (const char*)En_b;

    // ---- issue B tile 0 staging immediately (overlaps z-norm below) ----
#pragma unroll
    for (int i = 0; i < 4; ++i) {
        int chunk = i * 8 + wid;            // 0..31 (1KB chunks)
        int G   = chunk * 64 + lane;
        int row = G >> 5;
        int g   = (G & 31) ^ (row & 7);
        GLOAD16(eb + (size_t)row * 512 + g * 16, Bs0 + chunk * 1024);
    }

    // ---- fused z normalize -> bf16 -> swizzled As ----
    {
        const int zrow = tid >> 2;          // 0..127
        const int zq   = tid & 3;           // quarter of the row (64 floats)
        const float4* zr = (const float4*)(z + (size_t)(m0 + zrow) * DDIM + zq * 64);
        float ssq = 0.f;
#pragma unroll
        for (int i = 0; i < 16; ++i) {
            float4 v = zr[i];
            ssq += v.x * v.x + v.y * v.y + v.z * v.z + v.w * v.w;
        }
        ssq += __shfl_xor(ssq, 1);
        ssq += __shfl_xor(ssq, 2);
        float inv = 1.f / fmaxf(sqrtf(ssq), 1e-8f);
        int sw = zrow & 7;
#pragma unroll
        for (int j = 0; j < 8; ++j) {
            float4 v0 = zr[j * 2], v1 = zr[j * 2 + 1];
            short8 s8;
            s8[0] = (short)f2bf(v0.x * inv); s8[1] = (short)f2bf(v0.y * inv);
            s8[2] = (short)f2bf(v0.z * inv); s8[3] = (short)f2bf(v0.w * inv);
            s8[4] = (short)f2bf(v1.x * inv); s8[5] = (short)f2bf(v1.y * inv);
            s8[6] = (short)f2bf(v1.z * inv); s8[7] = (short)f2bf(v1.w * inv);
            int gd = zq * 8 + j;
            *(short8*)&As[zrow * 256 + ((gd ^ sw) * 8)] = s8;
        }
    }
    asm volatile("s_waitcnt vmcnt(0)");
    __syncthreads();

    // ---- A fragments -> registers: af[mi][ks], row = wr*32 + mi*16 + lo ----
    short8 af[2][8];
#pragma unroll
    for (int mi = 0; mi < 2; ++mi) {
        int row = wr * 32 + mi * 16 + lo;
        int sw  = row & 7;
#pragma unroll
        for (int ks = 0; ks < 8; ++ks) {
            int g = (ks * 4 + hi) ^ sw;
            af[mi][ks] = *(const short8*)&As[row * 256 + g * 8];
        }
    }

    float pmax[2][4], thrv[2][4];
#pragma unroll
    for (int mi = 0; mi < 2; ++mi)
#pragma unroll
        for (int r = 0; r < 4; ++r) { pmax[mi][r] = -FLT_MAX; thrv[mi][r] = FLT_MAX; }

    int cur = 0;
    for (int t = 0; t < NTILES; ++t) {
        // prefetch next B tile
        if (t + 1 < NTILES) {
            int kt1 = (t + 1) * BN;
            char* dst = cur ? Bs0 : Bs1;
#pragma unroll
            for (int i = 0; i < 4; ++i) {
                int chunk = i * 8 + wid;
                int G   = chunk * 64 + lane;
                int row = G >> 5;
                int g   = (G & 31) ^ (row & 7);
                GLOAD16(eb + (size_t)(kt1 + row) * 512 + g * 16, dst + chunk * 1024);
            }
        }

        f32x4 acc[2][2];
#pragma unroll
        for (int mi = 0; mi < 2; ++mi)
#pragma unroll
            for (int nj = 0; nj < 2; ++nj) acc[mi][nj] = (f32x4){0.f, 0.f, 0.f, 0.f};

        const unsigned short* Bc = (const unsigned short*)(cur ? Bs1 : Bs0);
#pragma unroll
        for (int ks = 0; ks < 8; ++ks) {
            short8 bf0, bf1;
            {
                int row = wc * 32 + lo;
                int g   = (ks * 4 + hi) ^ (row & 7);
                bf0 = *(const short8*)&Bc[row * 256 + g * 8];
            }
            {
                int row = wc * 32 + 16 + lo;
                int g   = (ks * 4 + hi) ^ (row & 7);
                bf1 = *(const short8*)&Bc[row * 256 + g * 8];
            }
#pragma unroll
            for (int mi = 0; mi < 2; ++mi) {
                acc[mi][0] = __builtin_amdgcn_mfma_f32_16x16x32_bf16(af[mi][ks], bf0, acc[mi][0], 0, 0, 0);
                acc[mi][1] = __builtin_amdgcn_mfma_f32_16x16x32_bf16(af[mi][ks], bf1, acc[mi][1], 0, 0, 0);
            }
        }

        // per-lane prefix-max fold (registers only)
#pragma unroll
        for (int mi = 0; mi < 2; ++mi)
#pragma unroll
            for (int r = 0; r < 4; ++r)
                pmax[mi][r] = fmaxf(pmax[mi][r], fmaxf(acc[mi][0][r], acc[mi][1][r]));

        const bool syncT = (t == 0) || ((t & 7) == 7);
        if (syncT) {
            // quad-reduce over lo&3, then atomicMax completes the reduction
#pragma unroll
            for (int mi = 0; mi < 2; ++mi)
#pragma unroll
                for (int r = 0; r < 4; ++r) {
                    float w = pmax[mi][r];
                    w = fmaxf(w, __shfl_xor(w, 1));
                    w = fmaxf(w, __shfl_xor(w, 2));
                    if ((lane & 3) == 0)
                        atomicMax(&rowmaxKey[wr * 32 + mi * 16 + hi * 4 + r], fkey(w));
                }
        }

        __syncthreads();   // dbuf + (on sync tiles) rowmax visibility

        if (syncT) {
#pragma unroll
            for (int mi = 0; mi < 2; ++mi)
#pragma unroll
                for (int r = 0; r < 4; ++r)
                    thrv[mi][r] = fkey_inv(rowmaxKey[wr * 32 + mi * 16 + hi * 4 + r]) - DELTA;
        }

        // candidate check vs (conservative) threshold
        const int kt = t * BN;
#pragma unroll
        for (int mi = 0; mi < 2; ++mi)
#pragma unroll
            for (int r = 0; r < 4; ++r) {
                int rloc = wr * 32 + mi * 16 + hi * 4 + r;
#pragma unroll
                for (int nj = 0; nj < 2; ++nj) {
                    if (acc[mi][nj][r] >= thrv[mi][r]) {
                        int pos = atomicAdd(&cnt[rloc], 1);
                        if (pos < CAP) list[rloc * CAP + pos] = kt + wc * 32 + nj * 16 + lo;
                    }
                }
            }

        cur ^= 1;
    }
    __syncthreads();   // lists complete

    // ---- exact fp32 rescore (order-independent, deterministic) ----
    for (int rr = 0; rr < 16; ++rr) {
        int rloc = wid * 16 + rr;
        int m = m0 + rloc;
        int n = cnt[rloc];
        float bv = -FLT_MAX;
        int   bk = 0x7fffffff;
        const float4 zz = *(const float4*)&z[(size_t)m * DDIM + lane * 4];
        if (n <= CAP) {
            for (int c = 0; c < n; ++c) {
                int k = list[rloc * CAP + c];
                const float4 ee = *(const float4*)&En[(size_t)k * DDIM + lane * 4];
                float s = zz.x * ee.x + zz.y * ee.y + zz.z * ee.z + zz.w * ee.w;
#pragma unroll
                for (int off = 1; off < 64; off <<= 1) s += __shfl_xor(s, off);
                if (s > bv || (s == bv && k < bk)) { bv = s; bk = k; }
            }
        } else {
            // fallback: full fp32 scan, z row staged in LDS (B-dbuf is dead here)
            float* zl = (float*)(Bs0 + wid * 1024);
            *(float4*)&zl[lane * 4] = zz;
            for (int kb = 0; kb < K_CODES; kb += 64) {
                int k = kb + lane;
                const float4* er = (const float4*)&En[(size_t)k * DDIM];
                float s0 = 0.f, s1 = 0.f, s2 = 0.f, s3 = 0.f;
#pragma unroll 8
                for (int d4 = 0; d4 < 64; ++d4) {
                    float4 e  = er[d4];
                    float4 zv = *(const float4*)&zl[d4 * 4];
                    s0 += zv.x * e.x; s1 += zv.y * e.y;
                    s2 += zv.z * e.z; s3 += zv.w * e.w;
                }
                float s = (s0 + s1) + (s2 + s3);
                if (s > bv || (s == bv && k < bk)) { bv = s; bk = k; }
            }
#pragma unroll
            for (int off = 1; off < 64; off <<= 1) {
                float ov = __shfl_xor(bv, off);
                int   ok = __shfl_xor(bk, off);
                if (ov > bv || (ov == bv && ok < bk)) { bv = ov; bk = ok; }
            }
        }
        if (lane == 0) bestIdx[m] = bk;
    }
}

// ---------------- kernel 3: gather / zq_st / per-row loss / idx ----------------
__global__ __launch_bounds__(256) void k_final(const float* __restrict__ z,
                                               const float* __restrict__ E,
                                               const int* __restrict__ bestIdx,
                                               float* __restrict__ out,
                                               float* __restrict__ rowloss) {
    int wid  = threadIdx.x >> 6;
    int lane = threadIdx.x & 63;
    int m    = blockIdx.x * 4 + wid;
    int idx  = bestIdx[m];

    const float* zr = z + (size_t)m * DDIM;
    const float* er = E + (size_t)idx * DDIM;

    float zv[4], ev[4];
    float sz = 0.f, se = 0.f;
#pragma unroll
    for (int p = 0; p < 4; ++p) {
        zv[p] = zr[lane + 64 * p]; sz += zv[p] * zv[p];
        ev[p] = er[lane + 64 * p]; se += ev[p] * ev[p];
    }
#pragma unroll
    for (int off = 32; off >= 1; off >>= 1) {
        sz += __shfl_xor(sz, off);
        se += __shfl_xor(se, off);
    }
    float nz = fmaxf(sqrtf(sz), 1e-8f);
    float ne = fmaxf(sqrtf(se), 1e-8f);

    float rs = 0.f;
    float* zq = out + 1 + (size_t)m * DDIM;
#pragma unroll
    for (int p = 0; p < 4; ++p) {
        float zn = zv[p] / nz;
        float en = ev[p] / ne;
        float d  = en - zn;
        rs += d * d;
        zq[lane + 64 * p] = zv[p] + (ev[p] - zv[p]);
    }
#pragma unroll
    for (int off = 32; off >= 1; off >>= 1) rs += __shfl_xor(rs, off);

    if (lane == 0) {
        rowloss[m] = rs;
        out[1 + (size_t)M_ROWS * DDIM + m] = (float)idx;
    }
}

// ---------------- kernel 4: deterministic loss reduction ----------------
__global__ __launch_bounds__(256) void k_loss(const float* __restrict__ rowloss,
                                              float* __restrict__ out) {
    __shared__ double sm[256];
    double s = 0.0;
    for (int i = threadIdx.x; i < M_ROWS; i += 256) s += (double)rowloss[i];
    sm[threadIdx.x] = s;
    __syncthreads();
    for (int st = 128; st > 0; st >>= 1) {
        if (threadIdx.x < st) sm[threadIdx.x] += sm[threadIdx.x + st];
        __syncthreads();
    }
    if (threadIdx.x == 0) {
        float c = (float)(sm[0] / (double)((size_t)M_ROWS * DDIM));
        out[0] = c + 0.05f * c;
    }
}

extern "C" void kernel_launch(void* const* d_in, const int* in_sizes, int n_in,
                              void* d_out, int out_size, void* d_ws, size_t ws_size,
                              hipStream_t stream) {
    const float* z = (const float*)d_in[0];
    const float* E = (const float*)d_in[1];
    float* out = (float*)d_out;

    char* ws = (char*)d_ws;
    size_t off = 0;
    float*          En      = (float*)(ws + off);          off += (size_t)K_CODES * DDIM * 4;  // 8 MB
    unsigned short* En_b    = (unsigned short*)(ws + off); off += (size_t)K_CODES * DDIM * 2;  // 4 MB
    int*            bestIdx = (int*)(ws + off);            off += (size_t)M_ROWS * 4;          // 128 KB
    float*          rowloss = (float*)(ws + off);

    k_norm_E<<<K_CODES / 4, 256, 0, stream>>>(E, En, En_b);
    k_cand<<<M_ROWS / BM, 512, 0, stream>>>(En_b, z, En, bestIdx);
    k_final<<<M_ROWS / 4, 256, 0, stream>>>(z, E, bestIdx, out, rowloss);
    k_loss<<<1, 256, 0, stream>>>(rowloss, out);
}